// Round 9
// baseline (571.877 us; speedup 1.0000x reference)
//
#include <hip/hip_runtime.h>

#define N_TOK 16384
#define N_EMB 8192
#define DIM   512
#define KSPLIT 4

typedef __attribute__((ext_vector_type(8))) short bf16x8;
typedef __attribute__((ext_vector_type(16))) float f32x16;
typedef unsigned short u16;

__device__ __forceinline__ u16 f2bf(float f) {
    unsigned u = __float_as_uint(f);
    u += 0x7fffu + ((u >> 16) & 1u);
    return (u16)(u >> 16);
}
__device__ __forceinline__ float bf2f(u16 h) {
    return __uint_as_float(((unsigned)h) << 16);
}

__device__ __forceinline__ void gload16(const void* g, void* l) {
    __builtin_amdgcn_global_load_lds(
        (const __attribute__((address_space(1))) unsigned int*)g,
        (__attribute__((address_space(3))) unsigned int*)l, 16, 0, 0);
}

// ---- prep: interleaved split layout: [row][16 kblocks][32 hi | 32 lo] bf16 (128 B lines)
__global__ void prep_x_kernel(const float* __restrict__ x, u16* __restrict__ xint) {
    const int tid = threadIdx.x, lane = tid & 63, wvi = tid >> 6;
    const int row = blockIdx.x * 4 + wvi;
    const float* src = x + (size_t)row * DIM + lane * 8;
    float4 v0 = *(const float4*)src;
    float4 v1 = *(const float4*)(src + 4);
    float vv[8] = {v0.x, v0.y, v0.z, v0.w, v1.x, v1.y, v1.z, v1.w};
    bf16x8 hv, lv;
#pragma unroll
    for (int i = 0; i < 8; ++i) {
        u16 h = f2bf(vv[i]);
        hv[i] = (short)h;
        lv[i] = (short)f2bf(vv[i] - bf2f(h));
    }
    u16* dst = xint + (size_t)row * 1024 + (lane >> 2) * 64 + (lane & 3) * 8;
    *(bf16x8*)dst = hv;
    *(bf16x8*)(dst + 32) = lv;
}

__global__ void prep_w_kernel(const float* __restrict__ w, u16* __restrict__ wint,
                              float* __restrict__ wsq) {
    const int tid = threadIdx.x, lane = tid & 63, wvi = tid >> 6;
    const int row = blockIdx.x * 4 + wvi;
    const float* src = w + (size_t)row * DIM + lane * 8;
    float4 v0 = *(const float4*)src;
    float4 v1 = *(const float4*)(src + 4);
    float vv[8] = {v0.x, v0.y, v0.z, v0.w, v1.x, v1.y, v1.z, v1.w};
    bf16x8 hv, lv;
    float s = 0.f;
#pragma unroll
    for (int i = 0; i < 8; ++i) {
        u16 h = f2bf(vv[i]);
        hv[i] = (short)h;
        lv[i] = (short)f2bf(vv[i] - bf2f(h));
        s += vv[i] * vv[i];
    }
    u16* dst = wint + (size_t)row * 1024 + (lane >> 2) * 64 + (lane & 3) * 8;
    *(bf16x8*)dst = hv;
    *(bf16x8*)(dst + 32) = lv;
#pragma unroll
    for (int off = 1; off < 64; off <<= 1) s += __shfl_xor(s, off);
    if (lane == 0) wsq[row] = s;
}

// ---- main: 3-pass split-bf16 GEMM, 32x32x16 MFMA, column-block LDS layout
//      (zero-conflict by contiguity, no swizzle), A triple-buf / B double-buf,
//      stage-at-top counted vmcnt, B-frag register prefetch, streaming argmin.
// LDS: A 3x16K + B 2x16K = 80 KiB -> exactly 2 blocks/CU.
// Plane layout: [8 k-octets][128 rows][16 B]; octets 0-3 = hi, 4-7 = lo.
#define MFMA3(d, ah_, al_, bh_, bl_)                                          \
    do {                                                                      \
        d = __builtin_amdgcn_mfma_f32_32x32x16_bf16(ah_, bh_, d, 0, 0, 0);    \
        d = __builtin_amdgcn_mfma_f32_32x32x16_bf16(ah_, bl_, d, 0, 0, 0);    \
        d = __builtin_amdgcn_mfma_f32_32x32x16_bf16(al_, bh_, d, 0, 0, 0);    \
    } while (0)

struct BSet { bf16x8 bh[2][2]; bf16x8 bl[2][2]; };

__global__ __launch_bounds__(256, 2)
void gemm_argmin_kernel(const u16* __restrict__ xint, const u16* __restrict__ wint,
                        const float* __restrict__ wsq,
                        float* __restrict__ wsval, int* __restrict__ wsidx) {
    __shared__ u16 smA[3][8192];   // 48 KiB: tile t in smA[t%3]
    __shared__ u16 smB[2][8192];   // 32 KiB: tile t in smB[t&1]
    const int tid = threadIdx.x;
    const int lane = tid & 63, wv = tid >> 6;
    const int wm = wv >> 1, wn = wv & 1;
    const int RB = blockIdx.x * 128;
    const int CB = blockIdx.y * 2048;
    const int l5 = lane >> 5, l31 = lane & 31;

    float runv[32];
    int   runi[32];
#pragma unroll
    for (int e = 0; e < 32; ++e) { runv[e] = 3.4e38f; runi[e] = 0; }

    const int rA0 = wm * 64 + l31;   // + mi*32
    const int rB0 = wn * 64 + l31;   // + ni*32

    // stage tile t: A -> smA[t%3], B -> smB[t&1]; 8 issues/wave (4 A + 4 B)
    auto stage = [&](int t) {
        u16* bA = &smA[t % 3][0];
        u16* bB = &smB[t & 1][0];
        const int kb = t & 15;
        const int cb = CB + (t >> 4) * 128;
#pragma unroll
        for (int i = 0; i < 4; ++i) {
            int j = wv * 4 + i;                 // 0..15, wave-uniform
            int g = j >> 1, rh = (j & 1) * 64;  // octet col, row half
            gload16(xint + (size_t)(RB + rh + lane) * 1024 + kb * 64 + g * 8,
                    bA + j * 512);
            gload16(wint + (size_t)(cb + rh + lane) * 1024 + kb * 64 + g * 8,
                    bB + j * 512);
        }
    };

#define READ_BSET(F, pB)                                                       \
    do {                                                                       \
        _Pragma("unroll") for (int ni = 0; ni < 2; ++ni)                       \
        _Pragma("unroll") for (int kk = 0; kk < 2; ++kk) {                     \
            int r_ = rB0 + ni * 32;                                            \
            (F).bh[ni][kk] = *(const bf16x8*)((pB) + (2 * kk + l5) * 1024 + r_ * 8);     \
            (F).bl[ni][kk] = *(const bf16x8*)((pB) + (2 * kk + l5 + 4) * 1024 + r_ * 8); \
        }                                                                      \
    } while (0)

    f32x16 acc[2][2];
    float wq0 = 0.f, wq1 = 0.f;
    BSet Fb0, Fb1;

    // prologue: stage tiles 0,1; prefetch B frags of tile 0
    stage(0);
    stage(1);
    asm volatile("s_waitcnt vmcnt(8)" ::: "memory");   // my stage(0) retired
    __builtin_amdgcn_s_barrier();                      // everyone's stage(0) done
    READ_BSET(Fb0, &smB[0][0]);
    asm volatile("s_waitcnt lgkmcnt(0)" ::: "memory");
    __builtin_amdgcn_sched_barrier(0);
    __builtin_amdgcn_s_barrier();                      // smB[0] reads done block-wide

#define STEP(CURB, NXTB, T)                                                    \
    do {                                                                       \
        const int t_ = (T);                                                    \
        if (t_ < 254) stage(t_ + 2);                                           \
        if (t_ >= 254)           { asm volatile("s_waitcnt vmcnt(0)" ::: "memory"); }  \
        else if ((t_ & 15) == 1) { asm volatile("s_waitcnt vmcnt(10)" ::: "memory"); } \
        else                     { asm volatile("s_waitcnt vmcnt(8)" ::: "memory"); }  \
        __builtin_amdgcn_s_barrier();                                          \
        if ((t_ & 15) == 0) {                                                  \
            const int c0_ = CB + (t_ >> 4) * 128 + wn * 64 + l31;              \
            wq0 = wsq[c0_]; wq1 = wsq[c0_ + 32];                               \
            _Pragma("unroll") for (int mi = 0; mi < 2; ++mi)                   \
            _Pragma("unroll") for (int ni = 0; ni < 2; ++ni)                   \
            _Pragma("unroll") for (int q = 0; q < 16; ++q) acc[mi][ni][q] = 0.f; \
        }                                                                      \
        const u16* pA_ = &smA[t_ % 3][0];                                      \
        bf16x8 ah[2][2], al[2][2];                                             \
        _Pragma("unroll") for (int kk = 0; kk < 2; ++kk)                       \
        _Pragma("unroll") for (int mi = 0; mi < 2; ++mi) {                     \
            int r_ = rA0 + mi * 32;                                            \
            ah[mi][kk] = *(const bf16x8*)(pA_ + (2 * kk + l5) * 1024 + r_ * 8);     \
            al[mi][kk] = *(const bf16x8*)(pA_ + (2 * kk + l5 + 4) * 1024 + r_ * 8); \
        }                                                                      \
        if (t_ < 255) { READ_BSET(NXTB, &smB[(t_ + 1) & 1][0]); }              \
        __builtin_amdgcn_s_setprio(1);                                         \
        _Pragma("unroll") for (int mi = 0; mi < 2; ++mi)                       \
        _Pragma("unroll") for (int ni = 0; ni < 2; ++ni) {                     \
            MFMA3(acc[mi][ni], ah[mi][0], al[mi][0], (CURB).bh[ni][0], (CURB).bl[ni][0]); \
        }                                                                      \
        _Pragma("unroll") for (int mi = 0; mi < 2; ++mi)                       \
        _Pragma("unroll") for (int ni = 0; ni < 2; ++ni) {                     \
            MFMA3(acc[mi][ni], ah[mi][1], al[mi][1], (CURB).bh[ni][1], (CURB).bl[ni][1]); \
        }                                                                      \
        __builtin_amdgcn_s_setprio(0);                                         \
        if ((t_ & 15) == 15) {                                                 \
            const int c0_ = CB + (t_ >> 4) * 128 + wn * 64 + l31;              \
            _Pragma("unroll") for (int mi = 0; mi < 2; ++mi)                   \
            _Pragma("unroll") for (int q = 0; q < 16; ++q) {                   \
                const int e = mi * 16 + q;                                     \
                float s0 = wq0 - 2.0f * acc[mi][0][q];                         \
                if (s0 < runv[e]) { runv[e] = s0; runi[e] = c0_; }             \
                float s1 = wq1 - 2.0f * acc[mi][1][q];                         \
                if (s1 < runv[e]) { runv[e] = s1; runi[e] = c0_ + 32; }        \
            }                                                                  \
        }                                                                      \
        asm volatile("s_waitcnt lgkmcnt(0)" ::: "memory");                     \
        __builtin_amdgcn_sched_barrier(0);                                     \
        __builtin_amdgcn_s_barrier();                                          \
    } while (0)

    for (int tt = 0; tt < 256; tt += 2) {
        STEP(Fb0, Fb1, tt);
        STEP(Fb1, Fb0, tt + 1);
    }
#undef STEP
#undef READ_BSET

    asm volatile("s_waitcnt vmcnt(0) lgkmcnt(0)" ::: "memory");
    __builtin_amdgcn_s_barrier();

    // cross-lane argmin reduce (32-lane halves; verified R4 mapping)
    float* mv  = (float*)&smA[0][0];                 // [2][128]
    int*   mi_ = (int*)((char*)&smA[0][0] + 1024);   // [2][128]
#pragma unroll
    for (int mi = 0; mi < 2; ++mi) {
#pragma unroll
        for (int q = 0; q < 16; ++q) {
            float v = runv[mi * 16 + q];
            int   ix = runi[mi * 16 + q];
#pragma unroll
            for (int off = 1; off < 32; off <<= 1) {
                float ov = __shfl_xor(v, off);
                int   oi = __shfl_xor(ix, off);
                if (ov < v || (ov == v && oi < ix)) { v = ov; ix = oi; }
            }
            if (l31 == 0) {
                int rl = wm * 64 + mi * 32 + (q & 3) + 8 * (q >> 2) + 4 * l5;
                mv[wn * 128 + rl]  = v;
                mi_[wn * 128 + rl] = ix;
            }
        }
    }
    __syncthreads();
    if (tid < 128) {
        float v0 = mv[tid];       int i0 = mi_[tid];
        float v1 = mv[128 + tid]; int i1 = mi_[128 + tid];
        if (v1 < v0 || (v1 == v0 && i1 < i0)) { v0 = v1; i0 = i1; }
        wsval[(size_t)(RB + tid) * KSPLIT + blockIdx.y] = v0;
        wsidx[(size_t)(RB + tid) * KSPLIT + blockIdx.y] = i0;
    }
}

// ---------------- merge ksplits + gather + loss partials ----------------
__global__ void gather_loss_kernel(const float* __restrict__ w, const float* __restrict__ x,
                                   const float* __restrict__ wsval, const int* __restrict__ wsidx,
                                   float* __restrict__ out, float* __restrict__ lossp) {
    const int tid = threadIdx.x, lane = tid & 63, wvi = tid >> 6;
    const int t = blockIdx.x * 4 + wvi;
    int bi = 0;
    if (lane == 0) {
        float bv = wsval[(size_t)t * KSPLIT];
        bi = wsidx[(size_t)t * KSPLIT];
#pragma unroll
        for (int ks = 1; ks < KSPLIT; ++ks) {
            float v = wsval[(size_t)t * KSPLIT + ks];
            int  ix = wsidx[(size_t)t * KSPLIT + ks];
            if (v < bv || (v == bv && ix < bi)) { bv = v; bi = ix; }
        }
    }
    bi = __shfl(bi, 0);
    const float* wr = w + (size_t)bi * DIM;
    const float* xr = x + (size_t)t * DIM;
    float* orow = out + (size_t)t * DIM;
    float s = 0.f;
#pragma unroll
    for (int j = 0; j < 2; ++j) {
        int d = j * 256 + lane * 4;
        float4 a = *(const float4*)(wr + d);
        float4 b = *(const float4*)(xr + d);
        *(float4*)(orow + d) = a;
        float d0 = a.x - b.x, d1 = a.y - b.y, d2 = a.z - b.z, d3 = a.w - b.w;
        s += d0 * d0 + d1 * d1 + d2 * d2 + d3 * d3;
    }
#pragma unroll
    for (int off = 1; off < 64; off <<= 1) s += __shfl_xor(s, off);
    __shared__ float ls[4];
    if (lane == 0) ls[wvi] = s;
    __syncthreads();
    if (tid == 0) lossp[blockIdx.x] = ls[0] + ls[1] + ls[2] + ls[3];
}

// ---------------- deterministic final loss reduce ----------------
__global__ void loss_final_kernel(const float* __restrict__ lossp, float* __restrict__ out) {
    __shared__ float red[256];
    float s = 0.f;
    for (int i = threadIdx.x; i < N_TOK / 4; i += 256) s += lossp[i];
    red[threadIdx.x] = s;
    __syncthreads();
    for (int st = 128; st > 0; st >>= 1) {
        if (threadIdx.x < st) red[threadIdx.x] += red[threadIdx.x + st];
        __syncthreads();
    }
    // vq_loss = (1 + BETA) * mean((q - x)^2)
    if (threadIdx.x == 0) out[(size_t)N_TOK * DIM] = red[0] * (1.25f / 8388608.f);
}

extern "C" void kernel_launch(void* const* d_in, const int* in_sizes, int n_in,
                              void* d_out, int out_size, void* d_ws, size_t ws_size,
                              hipStream_t stream) {
    const float* x = (const float*)d_in[0];   // [16384,512]
    const float* w = (const float*)d_in[1];   // [8192,512]
    float* out = (float*)d_out;               // 16384*512 + 1

    char* W = (char*)d_ws;
    u16*   xint  = (u16*)(W);                        // 32 MiB
    u16*   wint  = (u16*)(W + 33554432);             // 16 MiB
    float* wsq   = (float*)(W + 50331648);           // 32 KiB
    float* wsval = (float*)(W + 50364416);           // 256 KiB
    int*   wsidx = (int*)  (W + 50626560);           // 256 KiB
    float* lossp = (float*)(W + 50888704);           // 16 KiB

    prep_x_kernel<<<N_TOK / 4, 256, 0, stream>>>(x, xint);
    prep_w_kernel<<<N_EMB / 4, 256, 0, stream>>>(w, wint, wsq);
    dim3 g(N_TOK / 128, KSPLIT);
    gemm_argmin_kernel<<<g, 256, 0, stream>>>(xint, wint, wsq, wsval, wsidx);
    gather_loss_kernel<<<N_TOK / 4, 256, 0, stream>>>(w, x, wsval, wsidx, out, lossp);
    loss_final_kernel<<<1, 256, 0, stream>>>(lossp, out);
}